// Round 6
// baseline (22.951 us; speedup 1.0000x reference)
//
#include <hip/hip_runtime.h>
#include <math.h>

#define NN 2048
#define DD 64
#define BT 64             // output tile 64x64 -> 1024 blocks
#define CK 128            // C row length: [hi(64) | lo(64)] bf16

typedef short short8 __attribute__((ext_vector_type(8)));   // 8 bf16 patterns (4 VGPR)
typedef float f32x4 __attribute__((ext_vector_type(4)));
typedef unsigned short us4 __attribute__((ext_vector_type(4)));

__device__ inline unsigned short f2bf(float f) {            // fp32 -> bf16 RNE
    unsigned u = __float_as_uint(f);
    return (unsigned short)((u + 0x7FFFu + ((u >> 16) & 1u)) >> 16);
}
__device__ inline float bf2f(unsigned short b) {
    return __uint_as_float(((unsigned)b) << 16);
}

// Kernel 1: one-shot conversion  x(2048x64 f32) -> C(2048x128 bf16 [hi|lo])
// plus fp32 row norms. 16 lanes per row; norm via width-16 shuffle reduce.
__global__ __launch_bounds__(256) void prep(const float* __restrict__ x,
                                            unsigned short* __restrict__ C,
                                            float* __restrict__ nrm) {
    const int idx = blockIdx.x * 256 + threadIdx.x;   // 32768 threads: 1 float4 each
    const int row = idx >> 4;
    const int c4  = (idx & 15) << 2;
    float4 v = ((const float4*)x)[idx];
    unsigned short h0 = f2bf(v.x), h1 = f2bf(v.y), h2 = f2bf(v.z), h3 = f2bf(v.w);
    us4 hv = {h0, h1, h2, h3};
    us4 lv = {f2bf(v.x - bf2f(h0)), f2bf(v.y - bf2f(h1)),
              f2bf(v.z - bf2f(h2)), f2bf(v.w - bf2f(h3))};
    *(us4*)(C + (size_t)row * CK + c4)      = hv;
    *(us4*)(C + (size_t)row * CK + 64 + c4) = lv;
    float s = 0.f;
    s = fmaf(v.x, v.x, s); s = fmaf(v.y, v.y, s);
    s = fmaf(v.z, v.z, s); s = fmaf(v.w, v.w, s);
    s += __shfl_xor(s, 1, 16);
    s += __shfl_xor(s, 2, 16);
    s += __shfl_xor(s, 4, 16);
    s += __shfl_xor(s, 8, 16);
    if ((idx & 15) == 0) nrm[row] = s;
}

// Kernel 2: d(i,j) = sqrt(relu(n_i + n_j - 2*G_ij)), G = C·C^T via MFMA.
// NO LDS, NO barriers: fragments gathered per-lane from L2-resident C.
// C/D layout verified R3/R4: col=lane&15, row=(lane>>4)*4+reg.
// Diagonal written as exact 0 (reference is identically 0 there).
__global__ __launch_bounds__(256, 6) void cdist_g(const unsigned short* __restrict__ C,
                                                  const float* __restrict__ nrm,
                                                  float* __restrict__ out) {
    const int tid  = threadIdx.x;
    const int bi   = blockIdx.y * BT;
    const int bj   = blockIdx.x * BT;
    const int lane = tid & 63;
    const int wid  = tid >> 6;
    const int wm = wid >> 1, wn = wid & 1;   // 2x2 wave grid, 32x32 each
    const int lr = lane & 15;                // frag row (A) / col (B)
    const int lk = (lane >> 4) * 8;          // k-base within 32-frag

    const short8* A0 = (const short8*)(C + (size_t)(bi + wm * 32 + lr) * CK + lk);
    const short8* A1 = (const short8*)(C + (size_t)(bi + wm * 32 + 16 + lr) * CK + lk);
    const short8* B0 = (const short8*)(C + (size_t)(bj + wn * 32 + lr) * CK + lk);
    const short8* B1 = (const short8*)(C + (size_t)(bj + wn * 32 + 16 + lr) * CK + lk);

    f32x4 acc[2][2] = {};
    #pragma unroll
    for (int ks = 0; ks < 4; ++ks) {         // k step = 32 shorts = 4 short8
        short8 a0 = A0[ks * 4];
        short8 a1 = A1[ks * 4];
        short8 b0 = B0[ks * 4];
        short8 b1 = B1[ks * 4];
        acc[0][0] = __builtin_amdgcn_mfma_f32_16x16x32_bf16(a0, b0, acc[0][0], 0, 0, 0);
        acc[0][1] = __builtin_amdgcn_mfma_f32_16x16x32_bf16(a0, b1, acc[0][1], 0, 0, 0);
        acc[1][0] = __builtin_amdgcn_mfma_f32_16x16x32_bf16(a1, b0, acc[1][0], 0, 0, 0);
        acc[1][1] = __builtin_amdgcn_mfma_f32_16x16x32_bf16(a1, b1, acc[1][1], 0, 0, 0);
    }

    const float nb0 = nrm[bj + wn * 32 + lr];
    const float nb1 = nrm[bj + wn * 32 + 16 + lr];

    #pragma unroll
    for (int m = 0; m < 2; ++m) {
        #pragma unroll
        for (int g = 0; g < 4; ++g) {
            const int row = wm * 32 + m * 16 + (lane >> 4) * 4 + g;   // C/D row
            const int gi  = bi + row;
            const float na = nrm[gi];
            float* orow = out + (size_t)gi * NN + bj;
            const int col0 = wn * 32 + lr;                            // C/D col
            float v0 = na + nb0 - 2.f * acc[m][0][g];
            orow[col0] = (gi == bj + col0) ? 0.f : sqrtf(fmaxf(v0, 0.f));
            const int col1 = wn * 32 + 16 + lr;
            float v1 = na + nb1 - 2.f * acc[m][1][g];
            orow[col1] = (gi == bj + col1) ? 0.f : sqrtf(fmaxf(v1, 0.f));
        }
    }
}

extern "C" void kernel_launch(void* const* d_in, const int* in_sizes, int n_in,
                              void* d_out, int out_size, void* d_ws, size_t ws_size,
                              hipStream_t stream) {
    const float* x = (const float*)d_in[0];
    float* out = (float*)d_out;
    unsigned short* C = (unsigned short*)d_ws;                        // 512 KB
    float* nrm = (float*)((char*)d_ws + (size_t)NN * CK * 2);         // 8 KB
    prep<<<dim3(128), dim3(256), 0, stream>>>(x, C, nrm);
    cdist_g<<<dim3(NN / BT, NN / BT), dim3(256), 0, stream>>>(C, nrm, out);
}

// Round 7
// 13.464 us; speedup vs baseline: 1.7047x; 1.7047x over previous
//
#include <hip/hip_runtime.h>
#include <math.h>

#define NN 2048
#define DD 64
#define BT 64             // 64x64 output tile -> 1024 blocks, ~6 blocks/CU resident
#define LDK 72            // 64 bf16 + 8 pad = 144B row stride (odd # of 16B units)

typedef short short8 __attribute__((ext_vector_type(8)));   // 8 bf16 patterns (4 VGPR)
typedef float f32x4 __attribute__((ext_vector_type(4)));
typedef unsigned short us4 __attribute__((ext_vector_type(4)));

__device__ inline unsigned short f2bf(float f) {            // fp32 -> bf16 RNE
    unsigned u = __float_as_uint(f);
    return (unsigned short)((u + 0x7FFFu + ((u >> 16) & 1u)) >> 16);
}

// Single dispatch (R6 showed ~8us per extra dispatch). d2 = n_i + n_j - 2*G_ij
// with G from bf16 MFMA, K=64 (bf16-only: error <= ~0.02 in d, threshold 0.33).
// Diagonal written as exact 0. Norms fused into staging via width-16 shuffle.
// C/D layout verified R3/R4: col=lane&15, row=(lane>>4)*4+reg.
__global__ __launch_bounds__(256, 6) void cdist_bf16(const float* __restrict__ x,
                                                     float* __restrict__ out) {
    __shared__ unsigned short CA[BT][LDK];
    __shared__ unsigned short CB[BT][LDK];
    __shared__ float nrmA[BT], nrmB[BT];

    const int tid = threadIdx.x;
    const int bi = blockIdx.y * BT;
    const int bj = blockIdx.x * BT;

    // ---- stage panels as bf16 + fused fp32 row norms ----
    // 1024 float4 per panel; 16 consecutive lanes cover one row (16 float4).
    #pragma unroll
    for (int p = 0; p < 2; ++p) {
        const float4* src = (const float4*)(x + (size_t)(p ? bj : bi) * DD);
        unsigned short (*C)[LDK] = p ? CB : CA;
        float* nr = p ? nrmB : nrmA;
        #pragma unroll
        for (int s = 0; s < 4; ++s) {
            int idx = tid + s * 256;
            int row = idx >> 4;              // 16 float4 per 64-float row
            int c4  = (idx & 15) << 2;       // element offset in row
            float4 v = src[idx];
            us4 hv = {f2bf(v.x), f2bf(v.y), f2bf(v.z), f2bf(v.w)};
            *(us4*)(&C[row][c4]) = hv;       // ds_write_b64
            float sum = v.x * v.x;
            sum = fmaf(v.y, v.y, sum);
            sum = fmaf(v.z, v.z, sum);
            sum = fmaf(v.w, v.w, sum);
            sum += __shfl_xor(sum, 1, 16);
            sum += __shfl_xor(sum, 2, 16);
            sum += __shfl_xor(sum, 4, 16);
            sum += __shfl_xor(sum, 8, 16);
            if ((tid & 15) == 0) nr[row] = sum;
        }
    }
    __syncthreads();

    const int lane = tid & 63;
    const int wid  = tid >> 6;
    const int wm = wid >> 1, wn = wid & 1;   // 2x2 wave grid, 32x32 each
    const int lr = lane & 15;                // frag row (A) / col (B)
    const int lk = (lane >> 4) * 8;          // k-base within 32-frag

    // ---- gram: K=64 -> 2 k-steps, 8 ds_read_b128 + 8 MFMA per thread ----
    f32x4 acc[2][2] = {};
    #pragma unroll
    for (int ks = 0; ks < 2; ++ks) {
        const int k = ks * 32 + lk;
        short8 a0 = *(const short8*)(&CA[wm * 32 + lr][k]);
        short8 a1 = *(const short8*)(&CA[wm * 32 + 16 + lr][k]);
        short8 b0 = *(const short8*)(&CB[wn * 32 + lr][k]);
        short8 b1 = *(const short8*)(&CB[wn * 32 + 16 + lr][k]);
        acc[0][0] = __builtin_amdgcn_mfma_f32_16x16x32_bf16(a0, b0, acc[0][0], 0, 0, 0);
        acc[0][1] = __builtin_amdgcn_mfma_f32_16x16x32_bf16(a0, b1, acc[0][1], 0, 0, 0);
        acc[1][0] = __builtin_amdgcn_mfma_f32_16x16x32_bf16(a1, b0, acc[1][0], 0, 0, 0);
        acc[1][1] = __builtin_amdgcn_mfma_f32_16x16x32_bf16(a1, b1, acc[1][1], 0, 0, 0);
    }

    // ---- epilogue: d = sqrt(relu(nA + nB - 2G)); exact 0 on the diagonal ----
    const float nb0 = nrmB[wn * 32 + lr];
    const float nb1 = nrmB[wn * 32 + 16 + lr];
    #pragma unroll
    for (int m = 0; m < 2; ++m) {
        #pragma unroll
        for (int g = 0; g < 4; ++g) {
            const int row = wm * 32 + m * 16 + (lane >> 4) * 4 + g;   // C/D row
            const int gi  = bi + row;
            const float na = nrmA[row];
            float* orow = out + (size_t)gi * NN + bj;
            const int col0 = wn * 32 + lr;                            // C/D col
            const int col1 = col0 + 16;
            float v0 = na + nb0 - 2.f * acc[m][0][g];
            float v1 = na + nb1 - 2.f * acc[m][1][g];
            orow[col0] = (gi == bj + col0) ? 0.f : sqrtf(fmaxf(v0, 0.f));
            orow[col1] = (gi == bj + col1) ? 0.f : sqrtf(fmaxf(v1, 0.f));
        }
    }
}

extern "C" void kernel_launch(void* const* d_in, const int* in_sizes, int n_in,
                              void* d_out, int out_size, void* d_ws, size_t ws_size,
                              hipStream_t stream) {
    const float* x = (const float*)d_in[0];
    float* out = (float*)d_out;
    dim3 grid(NN / BT, NN / BT);   // 32 x 32 = 1024 blocks, ONE dispatch
    cdist_bf16<<<grid, dim3(256), 0, stream>>>(x, out);
}

// Round 9
// 12.291 us; speedup vs baseline: 1.8673x; 1.0954x over previous
//
#include <hip/hip_runtime.h>
#include <math.h>

#define NN 2048
#define DD 64
#define BT 64             // 64x64 output tile
#define NB (NN / BT)      // 32 tiles per side; triangle = 528 blocks
#define LDK 72            // 64 bf16 + 8 pad = 144B row stride

typedef short short8 __attribute__((ext_vector_type(8)));   // 8 bf16 patterns (4 VGPR)
typedef float f32x4 __attribute__((ext_vector_type(4)));
typedef unsigned short us4 __attribute__((ext_vector_type(4)));

__device__ inline unsigned short f2bf(float f) {            // fp32 -> bf16 RNE
    unsigned u = __float_as_uint(f);
    return (unsigned short)((u + 0x7FFFu + ((u >> 16) & 1u)) >> 16);
}

// Symmetric cdist: only upper-triangle tiles computed (528 blocks vs 1024);
// each tile stored twice: (i,j) with 64B-segment scalar stores and (j,i) with
// per-lane f32x4 stores (C/D layout gives each lane 4 consecutive rows at a
// fixed col -> contiguous along the transposed fast axis). G_ij==G_ji bitwise
// (same MFMA k-order, commutative products) so diagonal-block double-writes
// are benign. Diagonal written as exact 0. NT stores keep L2 for x.
__global__ __launch_bounds__(256, 6) void cdist_sym(const float* __restrict__ x,
                                                    float* __restrict__ out) {
    __shared__ unsigned short CA[BT][LDK];
    __shared__ unsigned short CB[BT][LDK];
    __shared__ float nrmA[BT], nrmB[BT];

    // ---- triangle decode: block t -> (u, v), u <= v ----
    int u = 0, rem = blockIdx.x, cnt = NB;
    while (rem >= cnt) { rem -= cnt; ++u; --cnt; }
    const int v = u + rem;
    const int bi = u * BT;
    const int bj = v * BT;

    const int tid = threadIdx.x;

    // ---- stage panels as bf16 + fused fp32 row norms ----
    #pragma unroll
    for (int p = 0; p < 2; ++p) {
        const float4* src = (const float4*)(x + (size_t)(p ? bj : bi) * DD);
        unsigned short (*C)[LDK] = p ? CB : CA;
        float* nr = p ? nrmB : nrmA;
        #pragma unroll
        for (int s = 0; s < 4; ++s) {
            int idx = tid + s * 256;
            int row = idx >> 4;
            int c4  = (idx & 15) << 2;
            float4 vv = src[idx];
            us4 hv = {f2bf(vv.x), f2bf(vv.y), f2bf(vv.z), f2bf(vv.w)};
            *(us4*)(&C[row][c4]) = hv;
            float sum = vv.x * vv.x;
            sum = fmaf(vv.y, vv.y, sum);
            sum = fmaf(vv.z, vv.z, sum);
            sum = fmaf(vv.w, vv.w, sum);
            sum += __shfl_xor(sum, 1, 16);
            sum += __shfl_xor(sum, 2, 16);
            sum += __shfl_xor(sum, 4, 16);
            sum += __shfl_xor(sum, 8, 16);
            if ((tid & 15) == 0) nr[row] = sum;
        }
    }
    __syncthreads();

    const int lane = tid & 63;
    const int wid  = tid >> 6;
    const int wm = wid >> 1, wn = wid & 1;   // 2x2 wave grid, 32x32 each
    const int lr = lane & 15;
    const int lk = (lane >> 4) * 8;

    // ---- gram: K=64 -> 8 ds_read_b128 + 8 MFMA per thread ----
    f32x4 acc[2][2] = {};
    #pragma unroll
    for (int ks = 0; ks < 2; ++ks) {
        const int k = ks * 32 + lk;
        short8 a0 = *(const short8*)(&CA[wm * 32 + lr][k]);
        short8 a1 = *(const short8*)(&CA[wm * 32 + 16 + lr][k]);
        short8 b0 = *(const short8*)(&CB[wn * 32 + lr][k]);
        short8 b1 = *(const short8*)(&CB[wn * 32 + 16 + lr][k]);
        acc[0][0] = __builtin_amdgcn_mfma_f32_16x16x32_bf16(a0, b0, acc[0][0], 0, 0, 0);
        acc[0][1] = __builtin_amdgcn_mfma_f32_16x16x32_bf16(a0, b1, acc[0][1], 0, 0, 0);
        acc[1][0] = __builtin_amdgcn_mfma_f32_16x16x32_bf16(a1, b0, acc[1][0], 0, 0, 0);
        acc[1][1] = __builtin_amdgcn_mfma_f32_16x16x32_bf16(a1, b1, acc[1][1], 0, 0, 0);
    }

    // ---- epilogue: d once, stored to (i,j) scalar + (j,i) f32x4 ----
    const float nb[2] = { nrmB[wn * 32 + lr], nrmB[wn * 32 + 16 + lr] };
    const int rbase = wm * 32 + (lane >> 4) * 4;            // + m*16 + g
    #pragma unroll
    for (int m = 0; m < 2; ++m) {
        #pragma unroll
        for (int n = 0; n < 2; ++n) {
            const int col = wn * 32 + n * 16 + lr;
            const int gj  = bj + col;
            f32x4 fd;
            #pragma unroll
            for (int g = 0; g < 4; ++g) {
                const int row = rbase + m * 16 + g;
                const int gi  = bi + row;
                float vv = nrmA[row] + nb[n] - 2.f * acc[m][n][g];
                float d = sqrtf(fmaxf(vv, 0.f));
                d = (gi == gj) ? 0.f : d;
                fd[g] = d;
                __builtin_nontemporal_store(d, out + (size_t)gi * NN + gj);
            }
            // transposed tile: 4 consecutive i at fixed j -> vector store
            __builtin_nontemporal_store(
                fd, (f32x4*)(out + (size_t)gj * NN + bi + rbase + m * 16));
        }
    }
}

extern "C" void kernel_launch(void* const* d_in, const int* in_sizes, int n_in,
                              void* d_out, int out_size, void* d_ws, size_t ws_size,
                              hipStream_t stream) {
    const float* x = (const float*)d_in[0];
    float* out = (float*)d_out;
    cdist_sym<<<dim3(NB * (NB + 1) / 2), dim3(256), 0, stream>>>(x, out);
}